// Round 3
// baseline (253.936 us; speedup 1.0000x reference)
//
#include <hip/hip_runtime.h>

#define D 256
#define S 2048
#define B 8
#define DSQ (D * D)   // 65536
#define INV3 (1.0f / 2043.0f)   // 1/(S-5)

typedef __bf16 bf16x8 __attribute__((ext_vector_type(8)));
typedef float f32x4 __attribute__((ext_vector_type(4)));

__device__ __forceinline__ unsigned short f2bf(float f) {
    union { float f; unsigned int u; } v; v.f = f;
    unsigned int u = v.u;
    u += 0x7fffu + ((u >> 16) & 1u);   // RTNE
    return (unsigned short)(u >> 16);
}

__device__ __forceinline__ void gl2lds16(const void* g, void* l) {
    __builtin_amdgcn_global_load_lds(
        (const __attribute__((address_space(1))) void*)g,
        (__attribute__((address_space(3))) void*)l, 16, 0, 0);
}

// ---------------- K1: bf16 cast + partial sums + Cbs build -----------------
// 512 blocks x 256 thr; block = 32 rows of one b. x is HBM-cold here — the
// one full-BW pass over x. Also re-arms the Tb flag for K23.
__global__ __launch_bounds__(256) void k_prep(const float* __restrict__ x,
                                              const float* __restrict__ comp,
                                              const float* __restrict__ basis,
                                              const float* __restrict__ root,
                                              unsigned short* __restrict__ xh,
                                              float* __restrict__ part,
                                              unsigned short* __restrict__ Cbs,
                                              unsigned int* __restrict__ flag) {
    int blk = blockIdx.x;            // b*64 + chunk
    int tid = threadIdx.x;
    int b = blk >> 6, chunk = blk & 63;
    __shared__ float ps[4][D];
    int rg = tid >> 6;               // 0..3 row-group (8 rows each)
    int c4 = (tid & 63) << 2;
    int row0 = chunk * 32 + rg * 8;
    const float4* xb = (const float4*)(x + ((size_t)b * S + row0) * D + c4);
    ushort4* dst = (ushort4*)(xh + ((size_t)(1 + b * S + row0)) * D + c4);
    float4 s = {0.f, 0.f, 0.f, 0.f};
    #pragma unroll
    for (int i = 0; i < 8; ++i) {
        float4 v = xb[(size_t)i * 64];
        ushort4 o;
        o.x = f2bf(v.x); o.y = f2bf(v.y); o.z = f2bf(v.z); o.w = f2bf(v.w);
        dst[(size_t)i * 64] = o;
        s.x += v.x; s.y += v.y; s.z += v.z; s.w += v.w;
    }
    *(float4*)&ps[rg][c4] = s;

    if (blk < 160) {                 // Cbs[step][n][32] bf16 (independent of x)
        int step = blk >> 2, q = blk & 3;
        int ji = step >> 3, kc = step & 7;
        int n = tid;
        float a0 = (ji == 2) ? 1.f : 0.f;
        float a1 = (ji == 1 || ji == 3) ? 0.5f : 0.f;
        float a2 = (ji == 0 || ji == 4) ? 0.5f : 0.f;
        float ar = (ji == 1) ? 1.f : 0.f;
        float cb0 = a0 * comp[0] + a1 * comp[2] + a2 * comp[4] - INV3 * comp[6];
        float cb1 = a0 * comp[1] + a1 * comp[3] + a2 * comp[5] - INV3 * comp[7];
        unsigned short buf[8];
        #pragma unroll
        for (int kk = 0; kk < 8; ++kk) {
            int i = kc * 32 + q * 8 + kk;
            buf[kk] = f2bf(cb0 * basis[i * D + n] + cb1 * basis[DSQ + i * D + n]
                           + ar * root[i * D + n]);
        }
        *(uint4*)(Cbs + ((size_t)step * 256 + n) * 32 + q * 8) = *(uint4*)buf;
    }
    if (blk == 0 && tid == 0) *flag = 0u;   // re-arm Tb handshake for K23
    __syncthreads();
    if (tid < 64)
        *(float4*)&part[(size_t)blk * D + tid * 4] =
            *(float4*)&ps[0][tid * 4] + *(float4*)&ps[1][tid * 4] +
            *(float4*)&ps[2][tid * 4] + *(float4*)&ps[3][tid * 4];
}

// ---------------- K23: old K3 + K2 folded AFTER the MFMA loop --------------
// CRITICAL codegen constraint (round-2 lesson): the region
// {stage -> __syncthreads -> frag prefetch -> 40-step loop} must stay
// EXACTLY as in the proven K3 — no divergent-barrier code before/inside it,
// or the bf16x8 arrays get demoted to scratch (VGPR_Count fell to 52,
// MfmaUtil 3.5%, 118 us). K2's work runs after the loop; Tb is published
// via an agent-scope release counter and consumed in the epilogue.
// 2 blocks/CU guaranteed (LDS 38912 B) => all 512 blocks co-resident =>
// the flag handshake cannot deadlock.
__global__ __launch_bounds__(256, 2) void k_bulk2(
        const unsigned short* __restrict__ xh,   // padded rows: [1 + B*S + 3]
        const unsigned short* __restrict__ Cbs,  // [40][256][32]
        const float* __restrict__ basis, const float* __restrict__ comp,
        const float* __restrict__ root, const float* __restrict__ bias,
        const float* __restrict__ part, const float* __restrict__ x,
        float* __restrict__ Tb, unsigned int* __restrict__ flag,
        float* __restrict__ out) {
    __shared__ __align__(16) unsigned short xs[68 * 256];   // 34816 B
    __shared__ __align__(16) float aux[4 * D];              // 4096 B (K2 scratch)
    const int tid  = threadIdx.x;
    const int lane = tid & 63;
    const int w    = tid >> 6;          // wave -> 32-col n sub-strip
    const int blk  = blockIdx.x;        // 0..511
    const int nblk = blk & 1;
    const int mblk = blk >> 1;          // 0..255
    const int bq   = mblk >> 5;
    const int t0   = (mblk & 31) << 6;
    const size_t rowbase = (size_t)bq * S + t0;   // padded row of x[bq][t0-1]

    // stage x tile: 68 rows x 512B = 2176 16B-chunks, swizzled
    #pragma unroll
    for (int q = 0; q < 8; ++q) {
        int F = (q * 256 + tid) * 16;
        int r = F >> 9;
        int c16 = (F >> 4) & 31;
        int gc = (c16 & 24) | ((c16 ^ r) & 7);
        gl2lds16((const char*)xh + ((rowbase + r) << 9) + (gc << 4), (char*)xs + F);
    }
    if (tid < 128) {
        int F = (2048 + tid) * 16;
        int r = F >> 9;
        int c16 = (F >> 4) & 31;
        int gc = (c16 & 24) | ((c16 ^ r) & 7);
        gl2lds16((const char*)xh + ((rowbase + r) << 9) + (gc << 4), (char*)xs + F);
    }
    __syncthreads();

    const int rlo = lane & 15, q4 = lane >> 4;
    const int nstrip = nblk * 128 + w * 32;

    #define BFRAG(st, nt) (*(const bf16x8*)(Cbs + \
        (((size_t)(st) * 256 + nstrip + (nt) * 16 + rlo) << 5) + (q4 << 3)))
    #define AFRAG(st, mt) (*(const bf16x8*)((const char*)xs + \
        ((((mt) * 16 + rlo + ((st) >> 3))) << 9) + \
        (((((st) & 7) * 4 + q4) & 24 | ((((st) & 7) * 4 + q4) ^ \
          ((mt) * 16 + rlo + ((st) >> 3))) & 7) << 4)))

    f32x4 acc[4][2] = {};
    bf16x8 bb[4][2];
    bf16x8 aa[2][4];
    #pragma unroll
    for (int nt = 0; nt < 2; ++nt) {
        bb[0][nt] = BFRAG(0, nt); bb[1][nt] = BFRAG(1, nt); bb[2][nt] = BFRAG(2, nt);
    }
    #pragma unroll
    for (int mt = 0; mt < 4; ++mt) aa[0][mt] = AFRAG(0, mt);

    #pragma unroll
    for (int step = 0; step < 40; ++step) {
        const int pfB = (step + 3 < 40) ? step + 3 : 39;
        #pragma unroll
        for (int nt = 0; nt < 2; ++nt) bb[(step + 3) & 3][nt] = BFRAG(pfB, nt);
        const int pfA = (step + 1 < 40) ? step + 1 : 39;
        #pragma unroll
        for (int mt = 0; mt < 4; ++mt) aa[(step + 1) & 1][mt] = AFRAG(pfA, mt);

        #pragma unroll
        for (int mt = 0; mt < 4; ++mt)
            #pragma unroll
            for (int nt = 0; nt < 2; ++nt)
                acc[mt][nt] = __builtin_amdgcn_mfma_f32_16x16x32_bf16(
                    aa[step & 1][mt], bb[step & 3][nt], acc[mt][nt], 0, 0, 0);
    }
    #undef BFRAG
    #undef AFRAG

    // ---- folded old-K2 work (after the loop; only acc[][] is live) ----
    if (blk < 8) {                           // Tb[b][o], single writer
        const int b = blk;
        float* tot = aux;
        float t = 0.f;
        #pragma unroll 8
        for (int c = 0; c < 64; ++c) t += part[(size_t)(b * 64 + c) * D + tid];
        tot[tid] = t;
        __syncthreads();
        int o = tid;
        float c30 = comp[6], c31 = comp[7];
        float a2c = 0.f;
        #pragma unroll 4
        for (int k = 0; k < D; ++k)
            a2c += tot[k] * (c30 * basis[k * D + o] + c31 * basis[DSQ + k * D + o]);
        Tb[b * D + o] = bias[o] + a2c * INV3;
        __syncthreads();                     // Tb stores drained (vmcnt)
        if (tid == 0)
            __hip_atomic_fetch_add(flag, 1u, __ATOMIC_RELEASE,
                                   __HIP_MEMORY_SCOPE_AGENT);
    } else if (blk < 40) {                   // boundary rows t=0,S-3,S-2,S-1
        const int r = blk - 8;
        const int tl[4] = {0, S - 3, S - 2, S - 1};
        const int t = tl[r & 3], b2 = r >> 2;
        float* z0 = aux; float* z1 = aux + D; float* xr = aux + 2 * D;
        const float* xb2 = x + (size_t)b2 * S * D;
        int i = tid;
        float tot2 = 0.f;
        #pragma unroll 8
        for (int c = 0; c < 64; ++c) tot2 += part[(size_t)(b2 * 64 + c) * D + i];
        float x_t = xb2[(size_t)t * D + i];
        float v0 = (t + 1 < S) ? xb2[(size_t)(t + 1) * D + i] : 0.f;
        float d1 = 1.f + ((t + 2 < S) ? 1.f : 0.f);
        float v1 = (x_t + ((t + 2 < S) ? xb2[(size_t)(t + 2) * D + i] : 0.f)) / d1;
        float s2 = ((t - 1 >= 0) ? xb2[(size_t)(t - 1) * D + i] : 0.f)
                 + ((t + 3 < S) ? xb2[(size_t)(t + 3) * D + i] : 0.f);
        int d2i = ((t - 1 >= 0) ? 1 : 0) + ((t + 3 < S) ? 1 : 0);
        float v2 = d2i ? s2 / (float)d2i : 0.f;
        float wsum = 0.f;
        for (int ss = t - 1; ss <= t + 3; ++ss)
            if (ss >= 0 && ss < S) wsum += xb2[(size_t)ss * D + i];
        int d3i = ((t - 1 > 0) ? (t - 1) : 0) + ((S - 4 - t > 0) ? (S - 4 - t) : 0);
        float v3 = d3i ? (tot2 - wsum) / (float)d3i : 0.f;
        z0[i] = comp[0] * v0 + comp[2] * v1 + comp[4] * v2 + comp[6] * v3;
        z1[i] = comp[1] * v0 + comp[3] * v1 + comp[5] * v2 + comp[7] * v3;
        xr[i] = x_t;
        __syncthreads();
        int o = tid;
        float a2c = 0.f;
        #pragma unroll 8
        for (int k = 0; k < D; ++k)
            a2c += z0[k] * basis[k * D + o] + z1[k] * basis[DSQ + k * D + o]
                 + xr[k] * root[k * D + o];
        out[(((size_t)b2 * S + t) << 8) + o] = a2c + bias[o];
    }

    // Tb ready? (producers finish ~2 us after the common GEMM tail)
    if (tid == 0) {
        while (__hip_atomic_load(flag, __ATOMIC_ACQUIRE,
                                 __HIP_MEMORY_SCOPE_AGENT) < 8u)
            __builtin_amdgcn_s_sleep(2);
    }
    __syncthreads();

    // epilogue: C/D layout col=lane&15, row=(lane>>4)*4+i
    const int col = lane & 15, rq = (lane >> 4) << 2;
    #pragma unroll
    for (int nt = 0; nt < 2; ++nt) {
        int n = nstrip + nt * 16 + col;
        float tb = Tb[bq * D + n];
        #pragma unroll
        for (int mt = 0; mt < 4; ++mt) {
            #pragma unroll
            for (int i = 0; i < 4; ++i) {
                int t = t0 + mt * 16 + rq + i;
                if (t >= 1 && t <= S - 4)
                    out[(((size_t)bq * S + t) << 8) + n] = acc[mt][nt][i] + tb;
            }
        }
    }
}

// ---------------- launch ----------------

extern "C" void kernel_launch(void* const* d_in, const int* in_sizes, int n_in,
                              void* d_out, int out_size, void* d_ws, size_t ws_size,
                              hipStream_t stream) {
    const float* x     = (const float*)d_in[0];
    const float* comp  = (const float*)d_in[1];
    const float* basis = (const float*)d_in[2];
    const float* root  = (const float*)d_in[3];
    const float* bias  = (const float*)d_in[4];
    float* out = (float*)d_out;

    // ws layout (no overlap):
    // part [0, 524288)  Tb [524288, 532480)  Cbs [532480, 1187840)
    // xh   [1187840, 1187840 + 16392*512)    flag [9580544, 9580548)
    char* ws = (char*)d_ws;
    float* part         = (float*)(ws);
    float* Tb           = (float*)(ws + 524288);
    unsigned short* Cbs = (unsigned short*)(ws + 532480);
    unsigned short* xh  = (unsigned short*)(ws + 1187840);
    unsigned int* flag  = (unsigned int*)(ws + 9580544);

    k_prep <<<512, 256, 0, stream>>>(x, comp, basis, root, xh, part, Cbs, flag);
    k_bulk2<<<512, 256, 0, stream>>>(xh, Cbs, basis, comp, root, bias, part, x,
                                     Tb, flag, out);
}

// Round 4
// 101.789 us; speedup vs baseline: 2.4947x; 2.4947x over previous
//
#include <hip/hip_runtime.h>

#define D 256
#define S 2048
#define B 8
#define DSQ (D * D)   // 65536
#define INV3 (1.0f / 2043.0f)   // 1/(S-5)

typedef __bf16 bf16x8 __attribute__((ext_vector_type(8)));
typedef float f32x4 __attribute__((ext_vector_type(4)));

__device__ __forceinline__ unsigned short f2bf(float f) {
    union { float f; unsigned int u; } v; v.f = f;
    unsigned int u = v.u;
    u += 0x7fffu + ((u >> 16) & 1u);   // RTNE
    return (unsigned short)(u >> 16);
}

__device__ __forceinline__ void gl2lds16(const void* g, void* l) {
    __builtin_amdgcn_global_load_lds(
        (const __attribute__((address_space(1))) void*)g,
        (__attribute__((address_space(3))) void*)l, 16, 0, 0);
}

// ---------------- K1: bf16 cast + tot atomics + Cbs build ------------------
// 512 blocks x 256 thr; block = 32 rows of one b. x is HBM-cold here — the
// one full-BW pass over x. tot[b][k] accumulated via device-scope f32
// atomicAdd (64 adds/address); tot is memset(0) on-stream before this kernel.
// Cbs extended to 48 steps: steps 40..47 carry +INV3*W3 (the Tb matvec,
// folded into the GEMM as a constant-over-rows A = tot_b).
__global__ __launch_bounds__(256) void k_prep(const float* __restrict__ x,
                                              const float* __restrict__ comp,
                                              const float* __restrict__ basis,
                                              const float* __restrict__ root,
                                              unsigned short* __restrict__ xh,
                                              float* __restrict__ tot,
                                              unsigned short* __restrict__ Cbs) {
    int blk = blockIdx.x;            // b*64 + chunk
    int tid = threadIdx.x;
    int b = blk >> 6, chunk = blk & 63;
    __shared__ float ps[4][D];
    int rg = tid >> 6;               // 0..3 row-group (8 rows each)
    int c4 = (tid & 63) << 2;
    int row0 = chunk * 32 + rg * 8;
    const float4* xb = (const float4*)(x + ((size_t)b * S + row0) * D + c4);
    ushort4* dst = (ushort4*)(xh + ((size_t)(1 + b * S + row0)) * D + c4);
    float4 s = {0.f, 0.f, 0.f, 0.f};
    #pragma unroll
    for (int i = 0; i < 8; ++i) {
        float4 v = xb[(size_t)i * 64];
        ushort4 o;
        o.x = f2bf(v.x); o.y = f2bf(v.y); o.z = f2bf(v.z); o.w = f2bf(v.w);
        dst[(size_t)i * 64] = o;
        s.x += v.x; s.y += v.y; s.z += v.z; s.w += v.w;
    }
    *(float4*)&ps[rg][c4] = s;

    if (blk < 192) {                 // Cbs[step][n][32] bf16, 48 steps
        int step = blk >> 2, q = blk & 3;
        int ji = step >> 3, kc = step & 7;
        int n = tid;
        float a0 = (ji == 2) ? 1.f : 0.f;
        float a1 = (ji == 1 || ji == 3) ? 0.5f : 0.f;
        float a2 = (ji == 0 || ji == 4) ? 0.5f : 0.f;
        float ar = (ji == 1) ? 1.f : 0.f;
        float s3 = (ji == 5) ? INV3 : -INV3;   // ji=5: +tot*W3*INV3 (ex-Tb)
        float cb0 = a0 * comp[0] + a1 * comp[2] + a2 * comp[4] + s3 * comp[6];
        float cb1 = a0 * comp[1] + a1 * comp[3] + a2 * comp[5] + s3 * comp[7];
        unsigned short buf[8];
        #pragma unroll
        for (int kk = 0; kk < 8; ++kk) {
            int i = kc * 32 + q * 8 + kk;
            buf[kk] = f2bf(cb0 * basis[i * D + n] + cb1 * basis[DSQ + i * D + n]
                           + ar * root[i * D + n]);
        }
        *(uint4*)(Cbs + ((size_t)step * 256 + n) * 32 + q * 8) = *(uint4*)buf;
    }
    __syncthreads();
    float v = ps[0][tid] + ps[1][tid] + ps[2][tid] + ps[3][tid];
    atomicAdd(tot + b * D + tid, v);
}

// ---------------- K2: boundary rows (blk<32, early return) + bulk GEMM -----
// Round-2/3 lesson: fragment arrays (acc/aa/bb) must NOT be live across any
// divergent-barrier region, or they get demoted to scratch (VGPR 52,
// MfmaUtil 2.3%, 15x slowdown). The boundary branch RETURNS before any
// fragment exists, so no live range crosses it. No inter-block waits remain
// (Tb folded into GEMM steps 40..47), so deadlock is impossible.
// 48-step loop is macro-unrolled with literal indices (no dynamic array
// indexing even if loop-unroll heuristics change).
__global__ __launch_bounds__(256, 2) void k_bulk(
        const unsigned short* __restrict__ xh,   // padded rows: [1 + B*S + 3]
        const unsigned short* __restrict__ Cbs,  // [48][256][32]
        const float* __restrict__ tot,           // [B][256] f32
        const float* __restrict__ basis, const float* __restrict__ root,
        const float* __restrict__ bias, const float* __restrict__ comp,
        const float* __restrict__ x, float* __restrict__ out) {
    __shared__ __align__(16) unsigned short xs[68 * 256];   // 34816 B
    __shared__ __align__(16) unsigned short tot_s[256];     // 512 B (bf16)
    const int tid = threadIdx.x;
    const int blk = blockIdx.x;        // 0..543

    if (blk < 32) {   // ---- boundary rows t in {0, S-3, S-2, S-1} ----
        const int q3 = blk & 3, b2 = blk >> 2;
        const int t = (q3 == 0) ? 0 : (S - 4 + q3);
        float* z0 = (float*)xs; float* z1 = z0 + D; float* xr = z0 + 2 * D;
        const float* xb2 = x + (size_t)b2 * S * D;
        const int i = tid;
        float tt = tot[b2 * D + i];
        float x_t = xb2[(size_t)t * D + i];
        float v0 = (t + 1 < S) ? xb2[(size_t)(t + 1) * D + i] : 0.f;
        float d1 = 1.f + ((t + 2 < S) ? 1.f : 0.f);
        float v1 = (x_t + ((t + 2 < S) ? xb2[(size_t)(t + 2) * D + i] : 0.f)) / d1;
        float s2 = ((t - 1 >= 0) ? xb2[(size_t)(t - 1) * D + i] : 0.f)
                 + ((t + 3 < S) ? xb2[(size_t)(t + 3) * D + i] : 0.f);
        int d2i = ((t - 1 >= 0) ? 1 : 0) + ((t + 3 < S) ? 1 : 0);
        float v2 = d2i ? s2 / (float)d2i : 0.f;
        float wsum = 0.f;
        for (int ss = t - 1; ss <= t + 3; ++ss)
            if (ss >= 0 && ss < S) wsum += xb2[(size_t)ss * D + i];
        int d3i = ((t - 1 > 0) ? (t - 1) : 0) + ((S - 4 - t > 0) ? (S - 4 - t) : 0);
        float v3 = d3i ? (tt - wsum) / (float)d3i : 0.f;
        z0[i] = comp[0] * v0 + comp[2] * v1 + comp[4] * v2 + comp[6] * v3;
        z1[i] = comp[1] * v0 + comp[3] * v1 + comp[5] * v2 + comp[7] * v3;
        xr[i] = x_t;
        __syncthreads();
        int o = tid;
        float a2c = 0.f;
        #pragma unroll 8
        for (int k = 0; k < D; ++k)
            a2c += z0[k] * basis[k * D + o] + z1[k] * basis[DSQ + k * D + o]
                 + xr[k] * root[k * D + o];
        out[(((size_t)b2 * S + t) << 8) + o] = a2c + bias[o];
        return;
    }

    // ---- bulk GEMM: block g = blk-32 in [0,512) ----
    const int g    = blk - 32;
    const int lane = tid & 63;
    const int w    = tid >> 6;          // wave -> 32-col n sub-strip
    const int nblk = g & 1;
    const int mblk = g >> 1;            // 0..255
    const int bq   = mblk >> 5;
    const int t0   = (mblk & 31) << 6;
    const size_t rowbase = (size_t)bq * S + t0;   // padded row of x[bq][t0-1]

    // stage x tile: 68 rows x 512B = 2176 16B-chunks, swizzled
    #pragma unroll
    for (int q = 0; q < 8; ++q) {
        int F = (q * 256 + tid) * 16;
        int r = F >> 9;
        int c16 = (F >> 4) & 31;
        int gc = (c16 & 24) | ((c16 ^ r) & 7);
        gl2lds16((const char*)xh + ((rowbase + r) << 9) + (gc << 4), (char*)xs + F);
    }
    if (tid < 128) {
        int F = (2048 + tid) * 16;
        int r = F >> 9;
        int c16 = (F >> 4) & 31;
        int gc = (c16 & 24) | ((c16 ^ r) & 7);
        gl2lds16((const char*)xh + ((rowbase + r) << 9) + (gc << 4), (char*)xs + F);
    }
    if (tid < 64) {   // stage tot_b as bf16 (A-operand of virtual steps 40..47)
        float4 tv = *(const float4*)(tot + bq * D + tid * 4);
        ushort4 o;
        o.x = f2bf(tv.x); o.y = f2bf(tv.y); o.z = f2bf(tv.z); o.w = f2bf(tv.w);
        *(ushort4*)(tot_s + tid * 4) = o;
    }
    __syncthreads();

    const int rlo = lane & 15, q4 = lane >> 4;
    const int nstrip = nblk * 128 + w * 32;

    #define BFRAG(st, nt) (*(const bf16x8*)(Cbs + \
        (((size_t)(st) * 256 + nstrip + (nt) * 16 + rlo) << 5) + (q4 << 3)))
    #define AFRAG(st, mt) (*(const bf16x8*)((const char*)xs + \
        ((((mt) * 16 + rlo + ((st) >> 3))) << 9) + \
        (((((st) & 7) * 4 + q4) & 24 | ((((st) & 7) * 4 + q4) ^ \
          ((mt) * 16 + rlo + ((st) >> 3))) & 7) << 4)))
    #define AVFRAG(kc) (*(const bf16x8*)((const char*)tot_s + ((kc) << 6) + (q4 << 4)))

    f32x4 acc[4][2] = {};
    bf16x8 bb[4][2];
    bf16x8 aa[2][4];
    #pragma unroll
    for (int nt = 0; nt < 2; ++nt) {
        bb[0][nt] = BFRAG(0, nt); bb[1][nt] = BFRAG(1, nt); bb[2][nt] = BFRAG(2, nt);
    }
    #pragma unroll
    for (int mt = 0; mt < 4; ++mt) aa[0][mt] = AFRAG(0, mt);

    #define MFMA8(s) \
        acc[0][0] = __builtin_amdgcn_mfma_f32_16x16x32_bf16(aa[(s)&1][0], bb[(s)&3][0], acc[0][0], 0, 0, 0); \
        acc[0][1] = __builtin_amdgcn_mfma_f32_16x16x32_bf16(aa[(s)&1][0], bb[(s)&3][1], acc[0][1], 0, 0, 0); \
        acc[1][0] = __builtin_amdgcn_mfma_f32_16x16x32_bf16(aa[(s)&1][1], bb[(s)&3][0], acc[1][0], 0, 0, 0); \
        acc[1][1] = __builtin_amdgcn_mfma_f32_16x16x32_bf16(aa[(s)&1][1], bb[(s)&3][1], acc[1][1], 0, 0, 0); \
        acc[2][0] = __builtin_amdgcn_mfma_f32_16x16x32_bf16(aa[(s)&1][2], bb[(s)&3][0], acc[2][0], 0, 0, 0); \
        acc[2][1] = __builtin_amdgcn_mfma_f32_16x16x32_bf16(aa[(s)&1][2], bb[(s)&3][1], acc[2][1], 0, 0, 0); \
        acc[3][0] = __builtin_amdgcn_mfma_f32_16x16x32_bf16(aa[(s)&1][3], bb[(s)&3][0], acc[3][0], 0, 0, 0); \
        acc[3][1] = __builtin_amdgcn_mfma_f32_16x16x32_bf16(aa[(s)&1][3], bb[(s)&3][1], acc[3][1], 0, 0, 0);

    #define KSTEP(s) { \
        bb[((s)+3)&3][0] = BFRAG((((s)+3) < 48) ? ((s)+3) : 47, 0); \
        bb[((s)+3)&3][1] = BFRAG((((s)+3) < 48) ? ((s)+3) : 47, 1); \
        if (((s)+1) < 40) { \
            aa[((s)+1)&1][0] = AFRAG(((s)+1) & 63, 0); \
            aa[((s)+1)&1][1] = AFRAG(((s)+1) & 63, 1); \
            aa[((s)+1)&1][2] = AFRAG(((s)+1) & 63, 2); \
            aa[((s)+1)&1][3] = AFRAG(((s)+1) & 63, 3); \
        } else { \
            bf16x8 av_ = AVFRAG((((s)+1) - 40) & 7); \
            aa[((s)+1)&1][0] = av_; aa[((s)+1)&1][1] = av_; \
            aa[((s)+1)&1][2] = av_; aa[((s)+1)&1][3] = av_; \
        } \
        MFMA8(s) }

    KSTEP(0)  KSTEP(1)  KSTEP(2)  KSTEP(3)  KSTEP(4)  KSTEP(5)  KSTEP(6)  KSTEP(7)
    KSTEP(8)  KSTEP(9)  KSTEP(10) KSTEP(11) KSTEP(12) KSTEP(13) KSTEP(14) KSTEP(15)
    KSTEP(16) KSTEP(17) KSTEP(18) KSTEP(19) KSTEP(20) KSTEP(21) KSTEP(22) KSTEP(23)
    KSTEP(24) KSTEP(25) KSTEP(26) KSTEP(27) KSTEP(28) KSTEP(29) KSTEP(30) KSTEP(31)
    KSTEP(32) KSTEP(33) KSTEP(34) KSTEP(35) KSTEP(36) KSTEP(37) KSTEP(38) KSTEP(39)
    KSTEP(40) KSTEP(41) KSTEP(42) KSTEP(43) KSTEP(44) KSTEP(45) KSTEP(46) KSTEP(47)

    #undef KSTEP
    #undef MFMA8
    #undef BFRAG
    #undef AFRAG
    #undef AVFRAG

    // epilogue: C/D layout col=lane&15, row=(lane>>4)*4+i ; bias in registers
    const int col = lane & 15, rq = (lane >> 4) << 2;
    #pragma unroll
    for (int nt = 0; nt < 2; ++nt) {
        int n = nstrip + nt * 16 + col;
        float bi = bias[n];
        #pragma unroll
        for (int mt = 0; mt < 4; ++mt) {
            #pragma unroll
            for (int i = 0; i < 4; ++i) {
                int t = t0 + mt * 16 + rq + i;
                if (t >= 1 && t <= S - 4)
                    out[(((size_t)bq * S + t) << 8) + n] = acc[mt][nt][i] + bi;
            }
        }
    }
}

// ---------------- launch ----------------

extern "C" void kernel_launch(void* const* d_in, const int* in_sizes, int n_in,
                              void* d_out, int out_size, void* d_ws, size_t ws_size,
                              hipStream_t stream) {
    const float* x     = (const float*)d_in[0];
    const float* comp  = (const float*)d_in[1];
    const float* basis = (const float*)d_in[2];
    const float* root  = (const float*)d_in[3];
    const float* bias  = (const float*)d_in[4];
    float* out = (float*)d_out;

    // ws layout (no overlap):
    // tot [0, 8192)  Cbs [8192, 8192+48*256*32*2=794624)
    // xh  [794624, 794624 + 16388*512 = 9185280)
    char* ws = (char*)d_ws;
    float* tot          = (float*)(ws);
    unsigned short* Cbs = (unsigned short*)(ws + 8192);
    unsigned short* xh  = (unsigned short*)(ws + 794624);

    hipMemsetAsync(tot, 0, B * D * sizeof(float), stream);   // re-arm atomics
    k_prep<<<512, 256, 0, stream>>>(x, comp, basis, root, xh, tot, Cbs);
    k_bulk<<<544, 256, 0, stream>>>(xh, Cbs, tot, basis, root, bias, comp, x, out);
}